// Round 10
// baseline (142.612 us; speedup 1.0000x reference)
//
#include <hip/hip_runtime.h>
#include <hip/hip_bf16.h>

#define NROWS 8192
#define DIM   128
#define NPAIR (NROWS / 2)
#define CSPLIT 32                        // col chunks -> partial[row][32]
#define COLS_PER_CS (NROWS / CSPLIT)     // 256 cols per block
#define CTILE 64                         // cols per LDS tile (16 KB)
#define NT (COLS_PER_CS / CTILE)         // 4 tiles per chunk
#define MREP 4                           // 16-row tiles per wave -> 64 rows
#define ROWS_PER_BLOCK 256               // 4 waves * 64 rows

typedef __attribute__((ext_vector_type(8))) short bf16x8;
typedef __attribute__((ext_vector_type(4))) float f32x4;

__device__ inline float exp2_fast(float x) {
#if __has_builtin(__builtin_amdgcn_exp2f)
    return __builtin_amdgcn_exp2f(x);
#else
    return exp2f(x);
#endif
}

__device__ inline unsigned short f2bf(float f) {
    unsigned int u = __float_as_uint(f);
    unsigned int r = (u + 0x7fffu + ((u >> 16) & 1u)) >> 16;
    return (unsigned short)r;
}

// Async global->LDS, 16B per lane. LDS dest must be wave-uniform base
// (HW writes lane i at base + i*16). Fallback: sync load + ds_write.
#if __has_builtin(__builtin_amdgcn_global_load_lds)
#define ASYNC16(gp, lp)                                                    \
    __builtin_amdgcn_global_load_lds(                                      \
        (const __attribute__((address_space(1))) void*)(gp),               \
        (__attribute__((address_space(3))) void*)(lp), 16, 0, 0)
#else
#define ASYNC16(gp, lp)                                                    \
    do { *(bf16x8*)((unsigned short*)(lp) + lane * 8) =                    \
             *(const bf16x8*)(gp); } while (0)
#endif

// exp(d/128 + 1) = e * exp2(d * SCL); SCL baked into A operand (Xa),
// the e factor folded into the partial write.
#define SCL_F 0.0112710550069450f      // log2(e)/128
#define E1_F  2.7182818284590452f

// Kernel 1: X (f32) -> Xa (bf16, scaled) and Xc (bf16, unscaled).
__global__ __launch_bounds__(256) void k_convert(const float* __restrict__ X,
                                                 unsigned short* __restrict__ Xa,
                                                 unsigned short* __restrict__ Xc) {
    int id = blockIdx.x * 256 + threadIdx.x;       // 0 .. 262143
    float4 v = reinterpret_cast<const float4*>(X)[id];
    ushort4 oa, oc;
    oa.x = f2bf(v.x * SCL_F); oa.y = f2bf(v.y * SCL_F);
    oa.z = f2bf(v.z * SCL_F); oa.w = f2bf(v.w * SCL_F);
    oc.x = f2bf(v.x); oc.y = f2bf(v.y); oc.z = f2bf(v.z); oc.w = f2bf(v.w);
    reinterpret_cast<ushort4*>(Xa)[id] = oa;
    reinterpret_cast<ushort4*>(Xc)[id] = oc;
}

#define MFMA16(A, B, D) __builtin_amdgcn_mfma_f32_16x16x32_bf16(A, B, D, 0, 0, 0)

// Kernel 2: partial[row][cs] = e * sum over 256-col chunk of exp2(SCL*dot).
// MREP=4 (A pinned in 64 VGPRs) halves LDS-read traffic vs R9; staging via
// global_load_lds (zero stage VGPRs, no VALU round-trip), double-buffered,
// issued before compute so L2 latency hides under MFMA+exp.
// Swizzle: linear LDS dest + pre-swizzled GLOBAL source + swizzled read
// (same involution seg^(col&7) on both sides -> bank-conflict-free, rule 21).
__global__ __launch_bounds__(256, 4)
void k_rowsum(const unsigned short* __restrict__ Xa,
              const unsigned short* __restrict__ Xc,
              float* __restrict__ partial) {
    __shared__ unsigned short Bt[2][CTILE * DIM];   // 2 x 16 KB
    const int tid  = threadIdx.x;
    const int wave = tid >> 6;
    const int lane = tid & 63;
    const int l15  = lane & 15;
    const int lhi  = lane >> 4;   // 0..3
    const int rowbase = blockIdx.x * ROWS_PER_BLOCK + wave * (MREP * 16);
    const int cs = blockIdx.y;
    const int c0 = cs * COLS_PER_CS;

    // A fragments: 4 row-tiles x 4 k-groups = 64 VGPRs, loaded once, pinned.
    bf16x8 a00, a01, a02, a03, a10, a11, a12, a13;
    bf16x8 a20, a21, a22, a23, a30, a31, a32, a33;
    {
        const unsigned short* r0 = Xa + (size_t)(rowbase + l15) * DIM + lhi * 8;
        const unsigned short* r1 = r0 + 16 * DIM;
        const unsigned short* r2 = r0 + 32 * DIM;
        const unsigned short* r3 = r0 + 48 * DIM;
        a00 = *(const bf16x8*)(r0);      a01 = *(const bf16x8*)(r0 + 32);
        a02 = *(const bf16x8*)(r0 + 64); a03 = *(const bf16x8*)(r0 + 96);
        a10 = *(const bf16x8*)(r1);      a11 = *(const bf16x8*)(r1 + 32);
        a12 = *(const bf16x8*)(r1 + 64); a13 = *(const bf16x8*)(r1 + 96);
        a20 = *(const bf16x8*)(r2);      a21 = *(const bf16x8*)(r2 + 32);
        a22 = *(const bf16x8*)(r2 + 64); a23 = *(const bf16x8*)(r2 + 96);
        a30 = *(const bf16x8*)(r3);      a31 = *(const bf16x8*)(r3 + 32);
        a32 = *(const bf16x8*)(r3 + 64); a33 = *(const bf16x8*)(r3 + 96);
    }
    asm volatile("" : "+v"(a00), "+v"(a01), "+v"(a02), "+v"(a03));
    asm volatile("" : "+v"(a10), "+v"(a11), "+v"(a12), "+v"(a13));
    asm volatile("" : "+v"(a20), "+v"(a21), "+v"(a22), "+v"(a23));
    asm volatile("" : "+v"(a30), "+v"(a31), "+v"(a32), "+v"(a33));

    f32x4 es0 = {0.f,0.f,0.f,0.f}, es1 = {0.f,0.f,0.f,0.f};
    f32x4 es2 = {0.f,0.f,0.f,0.f}, es3 = {0.f,0.f,0.f,0.f};

// Stage one 16KB tile: 1024 16B-chunks; wave w covers chunks j*256+w*64+lane.
// LDS dest linear (chunk id); global seg pre-swizzled by ^(col&7).
#define STAGE(BUF, TILE)                                                     \
    do {                                                                     \
        _Pragma("unroll")                                                    \
        for (int j = 0; j < 4; ++j) {                                        \
            int chunk = j * 256 + wave * 64 + lane;                          \
            int col   = chunk >> 4;                                          \
            int seg   = chunk & 15;                                          \
            const unsigned short* g = Xc +                                   \
                (size_t)(c0 + (TILE) * CTILE + col) * DIM +                  \
                ((seg ^ (col & 7)) * 8);                                     \
            ASYNC16(g, &Bt[BUF][(size_t)(j * 256 + wave * 64) * 8]);         \
        }                                                                    \
    } while (0)

#define DO_TILE(CUR)                                                         \
    do {                                                                     \
        const int x = l15 & 7;                                               \
        _Pragma("unroll")                                                    \
        for (int ct = 0; ct < CTILE / 16; ++ct) {                            \
            const unsigned short* lb = &Bt[CUR][(size_t)(ct * 16 + l15) * DIM]; \
            bf16x8 b0 = *(const bf16x8*)(lb + (((lhi     ) ^ x) * 8));       \
            bf16x8 b1 = *(const bf16x8*)(lb + (((lhi +  4) ^ x) * 8));       \
            bf16x8 b2 = *(const bf16x8*)(lb + (((lhi +  8) ^ x) * 8));       \
            bf16x8 b3 = *(const bf16x8*)(lb + (((lhi + 12) ^ x) * 8));       \
            f32x4 d0 = {0.f,0.f,0.f,0.f}, d1 = {0.f,0.f,0.f,0.f};            \
            f32x4 d2 = {0.f,0.f,0.f,0.f}, d3 = {0.f,0.f,0.f,0.f};            \
            d0 = MFMA16(a00, b0, d0); d1 = MFMA16(a10, b0, d1);              \
            d2 = MFMA16(a20, b0, d2); d3 = MFMA16(a30, b0, d3);              \
            d0 = MFMA16(a01, b1, d0); d1 = MFMA16(a11, b1, d1);              \
            d2 = MFMA16(a21, b1, d2); d3 = MFMA16(a31, b1, d3);              \
            d0 = MFMA16(a02, b2, d0); d1 = MFMA16(a12, b2, d1);              \
            d2 = MFMA16(a22, b2, d2); d3 = MFMA16(a32, b2, d3);              \
            d0 = MFMA16(a03, b3, d0); d1 = MFMA16(a13, b3, d1);              \
            d2 = MFMA16(a23, b3, d2); d3 = MFMA16(a33, b3, d3);              \
            es0[0] += exp2_fast(d0[0]); es0[1] += exp2_fast(d0[1]);          \
            es0[2] += exp2_fast(d0[2]); es0[3] += exp2_fast(d0[3]);          \
            es1[0] += exp2_fast(d1[0]); es1[1] += exp2_fast(d1[1]);          \
            es1[2] += exp2_fast(d1[2]); es1[3] += exp2_fast(d1[3]);          \
            es2[0] += exp2_fast(d2[0]); es2[1] += exp2_fast(d2[1]);          \
            es2[2] += exp2_fast(d2[2]); es2[3] += exp2_fast(d2[3]);          \
            es3[0] += exp2_fast(d3[0]); es3[1] += exp2_fast(d3[1]);          \
            es3[2] += exp2_fast(d3[2]); es3[3] += exp2_fast(d3[3]);          \
        }                                                                    \
    } while (0)

    STAGE(0, 0);
    asm volatile("s_waitcnt vmcnt(0)" ::: "memory");
    __syncthreads();

    int cur = 0;
    for (int t = 0; t < NT; ++t) {
        if (t + 1 < NT) STAGE(cur ^ 1, t + 1);   // issue-early (no wait)
        DO_TILE(cur);                            // compute hides load latency
        asm volatile("s_waitcnt vmcnt(0)" ::: "memory");
        __syncthreads();                         // next tile visible
        cur ^= 1;
    }

    // Reduce the 16 column-lanes (varying l15); one slot per row.
#pragma unroll
    for (int m = 0; m < MREP; ++m) {
#pragma unroll
        for (int j = 0; j < 4; ++j) {
            float v = (m == 0) ? es0[j] : (m == 1) ? es1[j]
                    : (m == 2) ? es2[j] : es3[j];
            v += __shfl_xor(v, 1, 64);
            v += __shfl_xor(v, 2, 64);
            v += __shfl_xor(v, 4, 64);
            v += __shfl_xor(v, 8, 64);
            if (l15 == 0) {
                int row = rowbase + m * 16 + lhi * 4 + j;
                partial[(size_t)row * CSPLIT + cs] = v * E1_F;
            }
        }
    }
}

// Kernel 3: per-pair exact f32 2x2 block + D_pos + J^2, block-reduced.
__global__ __launch_bounds__(256) void k_loss1(const float* __restrict__ X,
                                               const float* __restrict__ partial,
                                               float* __restrict__ lpart) {
    int p = blockIdx.x * 256 + threadIdx.x;   // 0..4095
    const float4* a = reinterpret_cast<const float4*>(X + (size_t)(2 * p) * DIM);
    const float4* b = reinterpret_cast<const float4*>(X + (size_t)(2 * p + 1) * DIM);
    float d00 = 0.f, d01 = 0.f, d11 = 0.f;
#pragma unroll 8
    for (int i = 0; i < DIM / 4; ++i) {
        float4 av = a[i], bv = b[i];
        d00 += av.x * av.x + av.y * av.y + av.z * av.z + av.w * av.w;
        d01 += av.x * bv.x + av.y * bv.y + av.z * bv.z + av.w * bv.w;
        d11 += bv.x * bv.x + bv.y * bv.y + bv.z * bv.z + bv.w * bv.w;
    }
    float D01 = d01 * (1.0f / DIM);
    float blocksum = __expf(d00 * (1.0f / DIM) + 1.0f)
                   + 2.0f * __expf(D01 + 1.0f)
                   + __expf(d11 * (1.0f / DIM) + 1.0f);

    const float4* pp = reinterpret_cast<const float4*>(partial + (size_t)(2 * p) * CSPLIT);
    float S = 0.0f;
#pragma unroll
    for (int i = 0; i < 2 * CSPLIT / 4; ++i) {
        float4 v = pp[i];
        S += v.x + v.y + v.z + v.w;
    }
    S -= blocksum;
    float J = logf(1e-8f + S) - D01;
    float t = fmaxf(J, 0.0f);
    float acc = t * t;

    __shared__ float red[4];
    float v = acc;
#pragma unroll
    for (int off = 32; off >= 1; off >>= 1) v += __shfl_down(v, off, 64);
    if ((threadIdx.x & 63) == 0) red[threadIdx.x >> 6] = v;
    __syncthreads();
    if (threadIdx.x == 0)
        lpart[blockIdx.x] = red[0] + red[1] + red[2] + red[3];
}

// Kernel 4: final 16-element sum -> loss.
__global__ __launch_bounds__(64) void k_final(const float* __restrict__ lpart,
                                              float* __restrict__ out) {
    float v = (threadIdx.x < 16) ? lpart[threadIdx.x] : 0.0f;
#pragma unroll
    for (int off = 8; off >= 1; off >>= 1) v += __shfl_down(v, off, 64);
    if (threadIdx.x == 0) out[0] = v * (1.0f / (2.0f * NPAIR));
}

extern "C" void kernel_launch(void* const* d_in, const int* in_sizes, int n_in,
                              void* d_out, int out_size, void* d_ws, size_t ws_size,
                              hipStream_t stream) {
    const float* X = (const float*)d_in[0];
    float* out = (float*)d_out;

    unsigned short* Xa = (unsigned short*)d_ws;                        // 2 MB
    unsigned short* Xc = Xa + (size_t)NROWS * DIM;                     // 2 MB
    float* partial = (float*)(Xc + (size_t)NROWS * DIM);               // 1 MB
    float* lpart = partial + (size_t)NROWS * CSPLIT;                   // 64 B

    k_convert<<<dim3((NROWS * DIM / 4) / 256), dim3(256), 0, stream>>>(X, Xa, Xc);
    k_rowsum<<<dim3(NROWS / ROWS_PER_BLOCK, CSPLIT), dim3(256), 0, stream>>>(Xa, Xc, partial);
    k_loss1<<<dim3(NPAIR / 256), dim3(256), 0, stream>>>(X, partial, lpart);
    k_final<<<dim3(1), dim3(64), 0, stream>>>(lpart, out);
}

// Round 11
// 56.248 us; speedup vs baseline: 2.5354x; 2.5354x over previous
//
#include <hip/hip_runtime.h>
#include <hip/hip_bf16.h>

#define NROWS 8192
#define DIM   128
#define NPAIR (NROWS / 2)
#define CSPLIT 32                        // col chunks -> partial[row][32]
#define COLS_PER_CS (NROWS / CSPLIT)     // 256 cols per block
#define CTILE 64                         // cols per LDS tile (16 KB)
#define NT (COLS_PER_CS / CTILE)         // 4 tiles per chunk
#define MREP 4                           // 16-row tiles per wave -> 64 rows
#define ROWS_PER_BLOCK 256               // 4 waves * 64 rows

typedef __attribute__((ext_vector_type(8))) short bf16x8;
typedef __attribute__((ext_vector_type(4))) float f32x4;

__device__ inline float exp2_fast(float x) {
#if __has_builtin(__builtin_amdgcn_exp2f)
    return __builtin_amdgcn_exp2f(x);
#else
    return exp2f(x);
#endif
}

__device__ inline unsigned short f2bf(float f) {
    unsigned int u = __float_as_uint(f);
    unsigned int r = (u + 0x7fffu + ((u >> 16) & 1u)) >> 16;
    return (unsigned short)r;
}

// Async global->LDS, 16B per lane (lane i lands at base + i*16).
#if __has_builtin(__builtin_amdgcn_global_load_lds)
#define ASYNC16(gp, lp)                                                    \
    __builtin_amdgcn_global_load_lds(                                      \
        (const __attribute__((address_space(1))) void*)(gp),               \
        (__attribute__((address_space(3))) void*)(lp), 16, 0, 0)
#else
#define ASYNC16(gp, lp)                                                    \
    do { *(bf16x8*)((unsigned short*)(lp) + lane * 8) =                    \
             *(const bf16x8*)(gp); } while (0)
#endif

// exp(d/128 + 1) = e * exp2(d * SCL); SCL baked into A operand (Xa),
// the e factor folded into the partial write.
#define SCL_F 0.0112710550069450f      // log2(e)/128
#define E1_F  2.7182818284590452f

// Kernel 1: X (f32) -> Xa (bf16, scaled) and Xc (bf16, unscaled).
__global__ __launch_bounds__(256) void k_convert(const float* __restrict__ X,
                                                 unsigned short* __restrict__ Xa,
                                                 unsigned short* __restrict__ Xc) {
    int id = blockIdx.x * 256 + threadIdx.x;       // 0 .. 262143
    float4 v = reinterpret_cast<const float4*>(X)[id];
    ushort4 oa, oc;
    oa.x = f2bf(v.x * SCL_F); oa.y = f2bf(v.y * SCL_F);
    oa.z = f2bf(v.z * SCL_F); oa.w = f2bf(v.w * SCL_F);
    oc.x = f2bf(v.x); oc.y = f2bf(v.y); oc.z = f2bf(v.z); oc.w = f2bf(v.w);
    reinterpret_cast<ushort4*>(Xa)[id] = oa;
    reinterpret_cast<ushort4*>(Xc)[id] = oc;
}

#define MFMA16(A, B, D) __builtin_amdgcn_mfma_f32_16x16x32_bf16(A, B, D, 0, 0, 0)

// Kernel 2: partial[row][cs] = e * sum over 256-col chunk of exp2(SCL*dot).
// A fragments (64 regs) pinned in the AGPR partition ("+a"): gfx950 MFMA
// reads A/B from AGPR natively, and this keeps the arch-VGPR partition
// (~60 regs: b/d/esum/addressing) spill-free. R10's "+v" pins forced all
// 64 into the 64-slot arch partition -> the 129MB/212MB spill storm.
__global__ __launch_bounds__(256)
void k_rowsum(const unsigned short* __restrict__ Xa,
              const unsigned short* __restrict__ Xc,
              float* __restrict__ partial) {
    __shared__ unsigned short Bt[2][CTILE * DIM];   // 2 x 16 KB
    const int tid  = threadIdx.x;
    const int wave = tid >> 6;
    const int lane = tid & 63;
    const int l15  = lane & 15;
    const int lhi  = lane >> 4;   // 0..3
    const int rowbase = blockIdx.x * ROWS_PER_BLOCK + wave * (MREP * 16);
    const int cs = blockIdx.y;
    const int c0 = cs * COLS_PER_CS;

    // A fragments: 4 row-tiles x 4 k-groups = 64 regs, loaded once,
    // pinned into AGPRs.
    bf16x8 a00, a01, a02, a03, a10, a11, a12, a13;
    bf16x8 a20, a21, a22, a23, a30, a31, a32, a33;
    {
        const unsigned short* r0 = Xa + (size_t)(rowbase + l15) * DIM + lhi * 8;
        const unsigned short* r1 = r0 + 16 * DIM;
        const unsigned short* r2 = r0 + 32 * DIM;
        const unsigned short* r3 = r0 + 48 * DIM;
        a00 = *(const bf16x8*)(r0);      a01 = *(const bf16x8*)(r0 + 32);
        a02 = *(const bf16x8*)(r0 + 64); a03 = *(const bf16x8*)(r0 + 96);
        a10 = *(const bf16x8*)(r1);      a11 = *(const bf16x8*)(r1 + 32);
        a12 = *(const bf16x8*)(r1 + 64); a13 = *(const bf16x8*)(r1 + 96);
        a20 = *(const bf16x8*)(r2);      a21 = *(const bf16x8*)(r2 + 32);
        a22 = *(const bf16x8*)(r2 + 64); a23 = *(const bf16x8*)(r2 + 96);
        a30 = *(const bf16x8*)(r3);      a31 = *(const bf16x8*)(r3 + 32);
        a32 = *(const bf16x8*)(r3 + 64); a33 = *(const bf16x8*)(r3 + 96);
    }
    asm volatile("" : "+a"(a00), "+a"(a01), "+a"(a02), "+a"(a03));
    asm volatile("" : "+a"(a10), "+a"(a11), "+a"(a12), "+a"(a13));
    asm volatile("" : "+a"(a20), "+a"(a21), "+a"(a22), "+a"(a23));
    asm volatile("" : "+a"(a30), "+a"(a31), "+a"(a32), "+a"(a33));

    f32x4 es0 = {0.f,0.f,0.f,0.f}, es1 = {0.f,0.f,0.f,0.f};
    f32x4 es2 = {0.f,0.f,0.f,0.f}, es3 = {0.f,0.f,0.f,0.f};

// Stage one 16KB tile: 1024 16B-chunks; wave w covers chunks j*256+w*64+lane.
// LDS dest linear (chunk id); global seg pre-swizzled by ^(col&7) so the
// swizzled ds_read below sees the right bytes (rule 21: both sides).
#define STAGE(BUF, TILE)                                                     \
    do {                                                                     \
        _Pragma("unroll")                                                    \
        for (int j = 0; j < 4; ++j) {                                        \
            int chunk = j * 256 + wave * 64 + lane;                          \
            int col   = chunk >> 4;                                          \
            int seg   = chunk & 15;                                          \
            const unsigned short* g = Xc +                                   \
                (size_t)(c0 + (TILE) * CTILE + col) * DIM +                  \
                ((seg ^ (col & 7)) * 8);                                     \
            ASYNC16(g, &Bt[BUF][(size_t)(j * 256 + wave * 64) * 8]);         \
        }                                                                    \
    } while (0)

#define DO_TILE(CUR)                                                         \
    do {                                                                     \
        const int x = l15 & 7;                                               \
        _Pragma("unroll")                                                    \
        for (int ct = 0; ct < CTILE / 16; ++ct) {                            \
            const unsigned short* lb = &Bt[CUR][(size_t)(ct * 16 + l15) * DIM]; \
            bf16x8 b0 = *(const bf16x8*)(lb + (((lhi     ) ^ x) * 8));       \
            bf16x8 b1 = *(const bf16x8*)(lb + (((lhi +  4) ^ x) * 8));       \
            bf16x8 b2 = *(const bf16x8*)(lb + (((lhi +  8) ^ x) * 8));       \
            bf16x8 b3 = *(const bf16x8*)(lb + (((lhi + 12) ^ x) * 8));       \
            f32x4 d0 = {0.f,0.f,0.f,0.f}, d1 = {0.f,0.f,0.f,0.f};            \
            f32x4 d2 = {0.f,0.f,0.f,0.f}, d3 = {0.f,0.f,0.f,0.f};            \
            d0 = MFMA16(a00, b0, d0); d1 = MFMA16(a10, b0, d1);              \
            d2 = MFMA16(a20, b0, d2); d3 = MFMA16(a30, b0, d3);              \
            d0 = MFMA16(a01, b1, d0); d1 = MFMA16(a11, b1, d1);              \
            d2 = MFMA16(a21, b1, d2); d3 = MFMA16(a31, b1, d3);              \
            d0 = MFMA16(a02, b2, d0); d1 = MFMA16(a12, b2, d1);              \
            d2 = MFMA16(a22, b2, d2); d3 = MFMA16(a32, b2, d3);              \
            d0 = MFMA16(a03, b3, d0); d1 = MFMA16(a13, b3, d1);              \
            d2 = MFMA16(a23, b3, d2); d3 = MFMA16(a33, b3, d3);              \
            es0[0] += exp2_fast(d0[0]); es0[1] += exp2_fast(d0[1]);          \
            es0[2] += exp2_fast(d0[2]); es0[3] += exp2_fast(d0[3]);          \
            es1[0] += exp2_fast(d1[0]); es1[1] += exp2_fast(d1[1]);          \
            es1[2] += exp2_fast(d1[2]); es1[3] += exp2_fast(d1[3]);          \
            es2[0] += exp2_fast(d2[0]); es2[1] += exp2_fast(d2[1]);          \
            es2[2] += exp2_fast(d2[2]); es2[3] += exp2_fast(d2[3]);          \
            es3[0] += exp2_fast(d3[0]); es3[1] += exp2_fast(d3[1]);          \
            es3[2] += exp2_fast(d3[2]); es3[3] += exp2_fast(d3[3]);          \
        }                                                                    \
    } while (0)

    STAGE(0, 0);
    asm volatile("s_waitcnt vmcnt(0)" ::: "memory");
    __syncthreads();

    int cur = 0;
    for (int t = 0; t < NT; ++t) {
        if (t + 1 < NT) STAGE(cur ^ 1, t + 1);   // issue-early (no wait)
        DO_TILE(cur);                            // compute hides load latency
        asm volatile("s_waitcnt vmcnt(0)" ::: "memory");
        __syncthreads();                         // next tile visible
        cur ^= 1;
    }

    // Reduce the 16 column-lanes (varying l15); one slot per row.
#pragma unroll
    for (int m = 0; m < MREP; ++m) {
#pragma unroll
        for (int j = 0; j < 4; ++j) {
            float v = (m == 0) ? es0[j] : (m == 1) ? es1[j]
                    : (m == 2) ? es2[j] : es3[j];
            v += __shfl_xor(v, 1, 64);
            v += __shfl_xor(v, 2, 64);
            v += __shfl_xor(v, 4, 64);
            v += __shfl_xor(v, 8, 64);
            if (l15 == 0) {
                int row = rowbase + m * 16 + lhi * 4 + j;
                partial[(size_t)row * CSPLIT + cs] = v * E1_F;
            }
        }
    }
}

// Kernel 3: per-pair exact f32 2x2 block + D_pos + J^2, block-reduced.
__global__ __launch_bounds__(256) void k_loss1(const float* __restrict__ X,
                                               const float* __restrict__ partial,
                                               float* __restrict__ lpart) {
    int p = blockIdx.x * 256 + threadIdx.x;   // 0..4095
    const float4* a = reinterpret_cast<const float4*>(X + (size_t)(2 * p) * DIM);
    const float4* b = reinterpret_cast<const float4*>(X + (size_t)(2 * p + 1) * DIM);
    float d00 = 0.f, d01 = 0.f, d11 = 0.f;
#pragma unroll 8
    for (int i = 0; i < DIM / 4; ++i) {
        float4 av = a[i], bv = b[i];
        d00 += av.x * av.x + av.y * av.y + av.z * av.z + av.w * av.w;
        d01 += av.x * bv.x + av.y * bv.y + av.z * bv.z + av.w * bv.w;
        d11 += bv.x * bv.x + bv.y * bv.y + bv.z * bv.z + bv.w * bv.w;
    }
    float D01 = d01 * (1.0f / DIM);
    float blocksum = __expf(d00 * (1.0f / DIM) + 1.0f)
                   + 2.0f * __expf(D01 + 1.0f)
                   + __expf(d11 * (1.0f / DIM) + 1.0f);

    const float4* pp = reinterpret_cast<const float4*>(partial + (size_t)(2 * p) * CSPLIT);
    float S = 0.0f;
#pragma unroll
    for (int i = 0; i < 2 * CSPLIT / 4; ++i) {
        float4 v = pp[i];
        S += v.x + v.y + v.z + v.w;
    }
    S -= blocksum;
    float J = logf(1e-8f + S) - D01;
    float t = fmaxf(J, 0.0f);
    float acc = t * t;

    __shared__ float red[4];
    float v = acc;
#pragma unroll
    for (int off = 32; off >= 1; off >>= 1) v += __shfl_down(v, off, 64);
    if ((threadIdx.x & 63) == 0) red[threadIdx.x >> 6] = v;
    __syncthreads();
    if (threadIdx.x == 0)
        lpart[blockIdx.x] = red[0] + red[1] + red[2] + red[3];
}

// Kernel 4: final 16-element sum -> loss.
__global__ __launch_bounds__(64) void k_final(const float* __restrict__ lpart,
                                              float* __restrict__ out) {
    float v = (threadIdx.x < 16) ? lpart[threadIdx.x] : 0.0f;
#pragma unroll
    for (int off = 8; off >= 1; off >>= 1) v += __shfl_down(v, off, 64);
    if (threadIdx.x == 0) out[0] = v * (1.0f / (2.0f * NPAIR));
}

extern "C" void kernel_launch(void* const* d_in, const int* in_sizes, int n_in,
                              void* d_out, int out_size, void* d_ws, size_t ws_size,
                              hipStream_t stream) {
    const float* X = (const float*)d_in[0];
    float* out = (float*)d_out;

    unsigned short* Xa = (unsigned short*)d_ws;                        // 2 MB
    unsigned short* Xc = Xa + (size_t)NROWS * DIM;                     // 2 MB
    float* partial = (float*)(Xc + (size_t)NROWS * DIM);               // 1 MB
    float* lpart = partial + (size_t)NROWS * CSPLIT;                   // 64 B

    k_convert<<<dim3((NROWS * DIM / 4) / 256), dim3(256), 0, stream>>>(X, Xa, Xc);
    k_rowsum<<<dim3(NROWS / ROWS_PER_BLOCK, CSPLIT), dim3(256), 0, stream>>>(Xa, Xc, partial);
    k_loss1<<<dim3(NPAIR / 256), dim3(256), 0, stream>>>(X, partial, lpart);
    k_final<<<dim3(1), dim3(64), 0, stream>>>(lpart, out);
}

// Round 12
// 50.189 us; speedup vs baseline: 2.8415x; 1.1207x over previous
//
#include <hip/hip_runtime.h>
#include <hip/hip_bf16.h>

#define NROWS 8192
#define DIM   128
#define NPAIR (NROWS / 2)
#define NB    64                         // 128-row groups
#define BROWS 128                        // rows/cols per block tile
#define CSPLIT 64                        // partial[row][64]
#define MREP  2                          // 16-row tiles per wave -> 32 rows
#define NCT   (BROWS / 16)               // 8 col-subtiles per block

typedef __attribute__((ext_vector_type(8))) short bf16x8;
typedef __attribute__((ext_vector_type(4))) float f32x4;

__device__ inline float exp2_fast(float x) {
#if __has_builtin(__builtin_amdgcn_exp2f)
    return __builtin_amdgcn_exp2f(x);
#else
    return exp2f(x);
#endif
}

__device__ inline unsigned short f2bf(float f) {
    unsigned int u = __float_as_uint(f);
    unsigned int r = (u + 0x7fffu + ((u >> 16) & 1u)) >> 16;
    return (unsigned short)r;
}

// exp(d/128 + 1) = e * exp2(d * SCL); SCL baked into A operand (Xa),
// the e factor folded into the partial writes.
#define SCL_F 0.0112710550069450f      // log2(e)/128
#define E1_F  2.7182818284590452f

// Kernel 1: X (f32) -> Xa (bf16, scaled) and Xc (bf16, unscaled).
__global__ __launch_bounds__(256) void k_convert(const float* __restrict__ X,
                                                 unsigned short* __restrict__ Xa,
                                                 unsigned short* __restrict__ Xc) {
    int id = blockIdx.x * 256 + threadIdx.x;       // 0 .. 262143
    float4 v = reinterpret_cast<const float4*>(X)[id];
    ushort4 oa, oc;
    oa.x = f2bf(v.x * SCL_F); oa.y = f2bf(v.y * SCL_F);
    oa.z = f2bf(v.z * SCL_F); oa.w = f2bf(v.w * SCL_F);
    oc.x = f2bf(v.x); oc.y = f2bf(v.y); oc.z = f2bf(v.z); oc.w = f2bf(v.w);
    reinterpret_cast<ushort4*>(Xa)[id] = oa;
    reinterpret_cast<ushort4*>(Xc)[id] = oc;
}

#define MFMA16(A, B, D) __builtin_amdgcn_mfma_f32_16x16x32_bf16(A, B, D, 0, 0, 0)

// Kernel 2 (SYMMETRY-HALVED): upper-triangle 128x128 tiles only.
// Block (bi,bj), bj>=bi: computes E-tile once; writes
//   row side: partial[bi-rows][bj]  (sum over tile cols)
//   col side: partial[bj-rows][bi]  (sum over tile rows; skipped if bi==bj)
// Every (row,chunk) slot written exactly once -> no init, deterministic.
// Structure = R9's allocator-proven shape: 32 pinned A regs/wave, 32KB
// reg-staged LDS tile (swizzled write + same-involution read), (256,4).
__global__ __launch_bounds__(256, 4)
void k_pairsum(const unsigned short* __restrict__ Xa,
               const unsigned short* __restrict__ Xc,
               float* __restrict__ partial) {
    const int bi = blockIdx.x;
    const int bj = blockIdx.y;
    if (bj < bi) return;

    __shared__ unsigned short Bt[BROWS * DIM];   // 32 KB
    __shared__ float colacc[4][BROWS];           // 2 KB
    const int tid  = threadIdx.x;
    const int wave = tid >> 6;
    const int lane = tid & 63;
    const int l15  = lane & 15;
    const int lhi  = lane >> 4;   // 0..3
    const int rowbase = bi * BROWS + wave * (MREP * 16);

    // Stage 32KB col-tile (bj-set, unscaled) into LDS: 2048 16B-chunks,
    // 8/thread in two 4-reg batches. LDS slot = (col<<4)|(seg^(col&7)).
    {
        const int tcol = tid >> 4, tseg = tid & 15;
        const int lslot = (tcol << 4) | (tseg ^ (tcol & 7));
        const unsigned short* g = Xc + (size_t)(bj * BROWS + tcol) * DIM + tseg * 8;
        bf16x8 s0 = *(const bf16x8*)(g);
        bf16x8 s1 = *(const bf16x8*)(g + 16 * DIM);
        bf16x8 s2 = *(const bf16x8*)(g + 32 * DIM);
        bf16x8 s3 = *(const bf16x8*)(g + 48 * DIM);
        *(bf16x8*)&Bt[(size_t)(lslot       ) * 8] = s0;
        *(bf16x8*)&Bt[(size_t)(lslot + 256 ) * 8] = s1;
        *(bf16x8*)&Bt[(size_t)(lslot + 512 ) * 8] = s2;
        *(bf16x8*)&Bt[(size_t)(lslot + 768 ) * 8] = s3;
        s0 = *(const bf16x8*)(g + 64 * DIM);
        s1 = *(const bf16x8*)(g + 80 * DIM);
        s2 = *(const bf16x8*)(g + 96 * DIM);
        s3 = *(const bf16x8*)(g + 112 * DIM);
        *(bf16x8*)&Bt[(size_t)(lslot + 1024) * 8] = s0;
        *(bf16x8*)&Bt[(size_t)(lslot + 1280) * 8] = s1;
        *(bf16x8*)&Bt[(size_t)(lslot + 1536) * 8] = s2;
        *(bf16x8*)&Bt[(size_t)(lslot + 1792) * 8] = s3;
    }

    // A fragments: 2 row-tiles x 4 k-groups = 32 VGPRs, pinned (R7/R9-proven).
    bf16x8 a00, a01, a02, a03, a10, a11, a12, a13;
    {
        const unsigned short* r0 = Xa + (size_t)(rowbase + l15) * DIM + lhi * 8;
        const unsigned short* r1 = r0 + 16 * DIM;
        a00 = *(const bf16x8*)(r0);      a01 = *(const bf16x8*)(r0 + 32);
        a02 = *(const bf16x8*)(r0 + 64); a03 = *(const bf16x8*)(r0 + 96);
        a10 = *(const bf16x8*)(r1);      a11 = *(const bf16x8*)(r1 + 32);
        a12 = *(const bf16x8*)(r1 + 64); a13 = *(const bf16x8*)(r1 + 96);
    }
    asm volatile("" : "+v"(a00), "+v"(a01), "+v"(a02), "+v"(a03));
    asm volatile("" : "+v"(a10), "+v"(a11), "+v"(a12), "+v"(a13));

    f32x4 es0 = {0.f,0.f,0.f,0.f}, es1 = {0.f,0.f,0.f,0.f};

    __syncthreads();                     // tile staged

    const int x = l15 & 7;               // read-side swizzle (involution)
#pragma unroll 2
    for (int ct = 0; ct < NCT; ++ct) {
        const unsigned short* lb = &Bt[(size_t)(ct * 16 + l15) * DIM];
        bf16x8 b0 = *(const bf16x8*)(lb + (((lhi     ) ^ x) * 8));
        bf16x8 b1 = *(const bf16x8*)(lb + (((lhi +  4) ^ x) * 8));
        bf16x8 b2 = *(const bf16x8*)(lb + (((lhi +  8) ^ x) * 8));
        bf16x8 b3 = *(const bf16x8*)(lb + (((lhi + 12) ^ x) * 8));

        f32x4 d0 = {0.f,0.f,0.f,0.f}, d1 = {0.f,0.f,0.f,0.f};
        d0 = MFMA16(a00, b0, d0); d1 = MFMA16(a10, b0, d1);
        d0 = MFMA16(a01, b1, d0); d1 = MFMA16(a11, b1, d1);
        d0 = MFMA16(a02, b2, d0); d1 = MFMA16(a12, b2, d1);
        d0 = MFMA16(a03, b3, d0); d1 = MFMA16(a13, b3, d1);

        float e0 = exp2_fast(d0[0]), e1 = exp2_fast(d0[1]);
        float e2 = exp2_fast(d0[2]), e3 = exp2_fast(d0[3]);
        float e4 = exp2_fast(d1[0]), e5 = exp2_fast(d1[1]);
        float e6 = exp2_fast(d1[2]), e7 = exp2_fast(d1[3]);
        es0[0] += e0; es0[1] += e1; es0[2] += e2; es0[3] += e3;
        es1[0] += e4; es1[1] += e5; es1[2] += e6; es1[3] += e7;

        // col-sum of this lane's 8 rows at col (ct*16+l15), then the other
        // 24 rows via lhi-shuffles; one store per ct, unique slot, no race.
        float cs = ((e0 + e1) + (e2 + e3)) + ((e4 + e5) + (e6 + e7));
        cs += __shfl_xor(cs, 16, 64);
        cs += __shfl_xor(cs, 32, 64);
        if (lhi == 0) colacc[wave][ct * 16 + l15] = cs;
    }

    // Row side: reduce 16 col-lanes; write partial[row][bj].
#pragma unroll
    for (int m = 0; m < MREP; ++m) {
#pragma unroll
        for (int j = 0; j < 4; ++j) {
            float v = (m == 0) ? es0[j] : es1[j];
            v += __shfl_xor(v, 1, 64);
            v += __shfl_xor(v, 2, 64);
            v += __shfl_xor(v, 4, 64);
            v += __shfl_xor(v, 8, 64);
            if (l15 == 0) {
                int row = rowbase + m * 16 + lhi * 4 + j;
                partial[(size_t)row * CSPLIT + bj] = v * E1_F;
            }
        }
    }

    // Col side (bi != bj): combine the 4 waves' 32-row col-sums.
    if (bi != bj) {
        __syncthreads();
        if (tid < BROWS) {
            float v = colacc[0][tid] + colacc[1][tid]
                    + colacc[2][tid] + colacc[3][tid];
            partial[(size_t)(bj * BROWS + tid) * CSPLIT + bi] = v * E1_F;
        }
    }
}

// Kernel 3: per-pair exact f32 2x2 block + D_pos + J^2, block-reduced.
__global__ __launch_bounds__(256) void k_loss1(const float* __restrict__ X,
                                               const float* __restrict__ partial,
                                               float* __restrict__ lpart) {
    int p = blockIdx.x * 256 + threadIdx.x;   // 0..4095
    const float4* a = reinterpret_cast<const float4*>(X + (size_t)(2 * p) * DIM);
    const float4* b = reinterpret_cast<const float4*>(X + (size_t)(2 * p + 1) * DIM);
    float d00 = 0.f, d01 = 0.f, d11 = 0.f;
#pragma unroll 8
    for (int i = 0; i < DIM / 4; ++i) {
        float4 av = a[i], bv = b[i];
        d00 += av.x * av.x + av.y * av.y + av.z * av.z + av.w * av.w;
        d01 += av.x * bv.x + av.y * bv.y + av.z * bv.z + av.w * bv.w;
        d11 += bv.x * bv.x + bv.y * bv.y + bv.z * bv.z + bv.w * bv.w;
    }
    float D01 = d01 * (1.0f / DIM);
    float blocksum = __expf(d00 * (1.0f / DIM) + 1.0f)
                   + 2.0f * __expf(D01 + 1.0f)
                   + __expf(d11 * (1.0f / DIM) + 1.0f);

    const float4* pp = reinterpret_cast<const float4*>(partial + (size_t)(2 * p) * CSPLIT);
    float S = 0.0f;
#pragma unroll
    for (int i = 0; i < 2 * CSPLIT / 4; ++i) {
        float4 v = pp[i];
        S += v.x + v.y + v.z + v.w;
    }
    S -= blocksum;
    float J = logf(1e-8f + S) - D01;
    float t = fmaxf(J, 0.0f);
    float acc = t * t;

    __shared__ float red[4];
    float v = acc;
#pragma unroll
    for (int off = 32; off >= 1; off >>= 1) v += __shfl_down(v, off, 64);
    if ((threadIdx.x & 63) == 0) red[threadIdx.x >> 6] = v;
    __syncthreads();
    if (threadIdx.x == 0)
        lpart[blockIdx.x] = red[0] + red[1] + red[2] + red[3];
}

// Kernel 4: final 16-element sum -> loss.
__global__ __launch_bounds__(64) void k_final(const float* __restrict__ lpart,
                                              float* __restrict__ out) {
    float v = (threadIdx.x < 16) ? lpart[threadIdx.x] : 0.0f;
#pragma unroll
    for (int off = 8; off >= 1; off >>= 1) v += __shfl_down(v, off, 64);
    if (threadIdx.x == 0) out[0] = v * (1.0f / (2.0f * NPAIR));
}

extern "C" void kernel_launch(void* const* d_in, const int* in_sizes, int n_in,
                              void* d_out, int out_size, void* d_ws, size_t ws_size,
                              hipStream_t stream) {
    const float* X = (const float*)d_in[0];
    float* out = (float*)d_out;

    unsigned short* Xa = (unsigned short*)d_ws;                        // 2 MB
    unsigned short* Xc = Xa + (size_t)NROWS * DIM;                     // 2 MB
    float* partial = (float*)(Xc + (size_t)NROWS * DIM);               // 2 MB
    float* lpart = partial + (size_t)NROWS * CSPLIT;                   // 64 B

    k_convert<<<dim3((NROWS * DIM / 4) / 256), dim3(256), 0, stream>>>(X, Xa, Xc);
    k_pairsum<<<dim3(NB, NB), dim3(256), 0, stream>>>(Xa, Xc, partial);
    k_loss1<<<dim3(NPAIR / 256), dim3(256), 0, stream>>>(X, partial, lpart);
    k_final<<<dim3(1), dim3(64), 0, stream>>>(lpart, out);
}

// Round 13
// 43.858 us; speedup vs baseline: 3.2517x; 1.1444x over previous
//
#include <hip/hip_runtime.h>
#include <hip/hip_bf16.h>

#define NROWS 8192
#define DIM   128
#define NPAIR (NROWS / 2)
#define CSPLIT 32                        // col chunks -> partial[row][32]
#define COLS_PER_CS (NROWS / CSPLIT)     // 256 cols per chunk
#define NTILES (COLS_PER_CS / 16)        // 16 col-tiles per chunk
#define MREP 2                           // 16-row tiles per wave -> 32 rows
#define ROWS_PER_BLOCK 128               // 4 waves * 32 rows

typedef __attribute__((ext_vector_type(8))) short bf16x8;
typedef __attribute__((ext_vector_type(4))) float f32x4;

__device__ inline float exp2_fast(float x) {
#if __has_builtin(__builtin_amdgcn_exp2f)
    return __builtin_amdgcn_exp2f(x);
#else
    return exp2f(x);
#endif
}

__device__ inline unsigned short f2bf(float f) {
    unsigned int u = __float_as_uint(f);
    unsigned int r = (u + 0x7fffu + ((u >> 16) & 1u)) >> 16;
    return (unsigned short)r;
}

// exp(d/128 + 1) = e * exp2(d * SCL); SCL baked into the packed A array,
// e folded into the partial write.
#define SCL_F 0.0112710550069450f      // log2(e)/128
#define E1_F  2.7182818284590452f

// Kernel 1: pack X (f32) into MFMA-fragment order (verified correct in R6:
// absmax 0.0). Fragment f = tile*4+g holds, at [lane*8+e], element
// (row = tile*16 + (lane&15), k = g*32 + (lane>>4)*8 + e). A wave-load
// P[f*64+lane] is 64 lanes x 16B fully contiguous (8 full 128B lines).
// Pa = scaled by SCL (A operand), Pb = unscaled (B operand).
__global__ __launch_bounds__(256) void k_pack(const float* __restrict__ X,
                                              unsigned short* __restrict__ Pa,
                                              unsigned short* __restrict__ Pb) {
    int id = blockIdx.x * 256 + threadIdx.x;     // 0 .. 262143
    float4 v = reinterpret_cast<const float4*>(X)[id];
    int r  = id >> 5;                 // row 0..8191
    int k0 = (id & 31) * 4;           // 0,4,...,124
    int tile = r >> 4;
    int g    = k0 >> 5;               // 0..3
    int lhi  = (k0 >> 3) & 3;         // 0..3
    int e0   = k0 & 7;                // 0 or 4
    size_t base = ((size_t)(tile * 4 + g) * 64 + lhi * 16 + (r & 15)) * 8 + e0;
    ushort4 oa, ob;
    oa.x = f2bf(v.x * SCL_F); oa.y = f2bf(v.y * SCL_F);
    oa.z = f2bf(v.z * SCL_F); oa.w = f2bf(v.w * SCL_F);
    ob.x = f2bf(v.x); ob.y = f2bf(v.y); ob.z = f2bf(v.z); ob.w = f2bf(v.w);
    *reinterpret_cast<ushort4*>(Pa + base) = oa;
    *reinterpret_cast<ushort4*>(Pb + base) = ob;
}

#define MFMA16(A, B, D) __builtin_amdgcn_mfma_f32_16x16x32_bf16(A, B, D, 0, 0, 0)

// Kernel 2: partial[row][cs] = e * sum over 256-col chunk cs of exp2(SCL*dot).
// THE CLEAN LATENCY TEST: no LDS, no barriers; every load coalesced 1KB;
// A = 32 pinned VGPRs (R7-proven footprint, VGPR~52); 2048 blocks = 8/CU
// -> up to 8 waves/SIMD of independent streams to hide L2 latency. The 4
// waves of a block read IDENTICAL Pb addresses -> L1 broadcast.
__global__ void k_rowsum(const unsigned short* __restrict__ Pa,
                         const unsigned short* __restrict__ Pb,
                         float* __restrict__ partial) {
    const int wave = threadIdx.x >> 6;
    const int lane = threadIdx.x & 63;
    const int l15  = lane & 15;
    const int lhi  = lane >> 4;   // 0..3
    const int rowbase = blockIdx.x * ROWS_PER_BLOCK + wave * (MREP * 16);
    const int rb0 = rowbase >> 4;            // first 16-row tile of this wave
    const int cs  = blockIdx.y;

    const bf16x8* PA = reinterpret_cast<const bf16x8*>(Pa);
    const bf16x8* PB = reinterpret_cast<const bf16x8*>(Pb);

    // A fragments: 2 row-tiles x 4 k-groups = 32 VGPRs, coalesced, pinned.
    bf16x8 a00 = PA[(size_t)(rb0 * 4 + 0) * 64 + lane];
    bf16x8 a01 = PA[(size_t)(rb0 * 4 + 1) * 64 + lane];
    bf16x8 a02 = PA[(size_t)(rb0 * 4 + 2) * 64 + lane];
    bf16x8 a03 = PA[(size_t)(rb0 * 4 + 3) * 64 + lane];
    bf16x8 a10 = PA[(size_t)(rb0 * 4 + 4) * 64 + lane];
    bf16x8 a11 = PA[(size_t)(rb0 * 4 + 5) * 64 + lane];
    bf16x8 a12 = PA[(size_t)(rb0 * 4 + 6) * 64 + lane];
    bf16x8 a13 = PA[(size_t)(rb0 * 4 + 7) * 64 + lane];
    asm volatile("" : "+v"(a00), "+v"(a01), "+v"(a02), "+v"(a03));
    asm volatile("" : "+v"(a10), "+v"(a11), "+v"(a12), "+v"(a13));

    f32x4 esum0 = {0.f, 0.f, 0.f, 0.f};
    f32x4 esum1 = {0.f, 0.f, 0.f, 0.f};

    size_t tb = (size_t)cs * NTILES * 256 + lane;   // 256 frags16 per tile

    for (int ct = 0; ct < NTILES; ++ct) {
        bf16x8 b0 = PB[tb];
        bf16x8 b1 = PB[tb + 64];
        bf16x8 b2 = PB[tb + 128];
        bf16x8 b3 = PB[tb + 192];
        tb += 256;

        f32x4 d0 = {0.f, 0.f, 0.f, 0.f};
        f32x4 d1 = {0.f, 0.f, 0.f, 0.f};
        d0 = MFMA16(a00, b0, d0); d1 = MFMA16(a10, b0, d1);
        d0 = MFMA16(a01, b1, d0); d1 = MFMA16(a11, b1, d1);
        d0 = MFMA16(a02, b2, d0); d1 = MFMA16(a12, b2, d1);
        d0 = MFMA16(a03, b3, d0); d1 = MFMA16(a13, b3, d1);

        esum0[0] += exp2_fast(d0[0]); esum0[1] += exp2_fast(d0[1]);
        esum0[2] += exp2_fast(d0[2]); esum0[3] += exp2_fast(d0[3]);
        esum1[0] += exp2_fast(d1[0]); esum1[1] += exp2_fast(d1[1]);
        esum1[2] += exp2_fast(d1[2]); esum1[3] += exp2_fast(d1[3]);
    }

    // Reduce the 16 column-lanes (varying l15); one slot per row.
#pragma unroll
    for (int m = 0; m < MREP; ++m) {
#pragma unroll
        for (int j = 0; j < 4; ++j) {
            float v = (m == 0) ? esum0[j] : esum1[j];
            v += __shfl_xor(v, 1, 64);
            v += __shfl_xor(v, 2, 64);
            v += __shfl_xor(v, 4, 64);
            v += __shfl_xor(v, 8, 64);
            if (l15 == 0) {
                int row = rowbase + m * 16 + lhi * 4 + j;
                partial[(size_t)row * CSPLIT + cs] = v * E1_F;
            }
        }
    }
}

// Kernel 3: per-pair exact f32 2x2 block + D_pos + J^2, block-reduced.
__global__ __launch_bounds__(256) void k_loss1(const float* __restrict__ X,
                                               const float* __restrict__ partial,
                                               float* __restrict__ lpart) {
    int p = blockIdx.x * 256 + threadIdx.x;   // 0..4095
    const float4* a = reinterpret_cast<const float4*>(X + (size_t)(2 * p) * DIM);
    const float4* b = reinterpret_cast<const float4*>(X + (size_t)(2 * p + 1) * DIM);
    float d00 = 0.f, d01 = 0.f, d11 = 0.f;
#pragma unroll 8
    for (int i = 0; i < DIM / 4; ++i) {
        float4 av = a[i], bv = b[i];
        d00 += av.x * av.x + av.y * av.y + av.z * av.z + av.w * av.w;
        d01 += av.x * bv.x + av.y * bv.y + av.z * bv.z + av.w * bv.w;
        d11 += bv.x * bv.x + bv.y * bv.y + bv.z * bv.z + bv.w * bv.w;
    }
    float D01 = d01 * (1.0f / DIM);
    float blocksum = __expf(d00 * (1.0f / DIM) + 1.0f)
                   + 2.0f * __expf(D01 + 1.0f)
                   + __expf(d11 * (1.0f / DIM) + 1.0f);

    const float4* pp = reinterpret_cast<const float4*>(partial + (size_t)(2 * p) * CSPLIT);
    float S = 0.0f;
#pragma unroll
    for (int i = 0; i < 2 * CSPLIT / 4; ++i) {
        float4 v = pp[i];
        S += v.x + v.y + v.z + v.w;
    }
    S -= blocksum;
    float J = logf(1e-8f + S) - D01;
    float t = fmaxf(J, 0.0f);
    float acc = t * t;

    __shared__ float red[4];
    float v = acc;
#pragma unroll
    for (int off = 32; off >= 1; off >>= 1) v += __shfl_down(v, off, 64);
    if ((threadIdx.x & 63) == 0) red[threadIdx.x >> 6] = v;
    __syncthreads();
    if (threadIdx.x == 0)
        lpart[blockIdx.x] = red[0] + red[1] + red[2] + red[3];
}

// Kernel 4: final 16-element sum -> loss.
__global__ __launch_bounds__(64) void k_final(const float* __restrict__ lpart,
                                              float* __restrict__ out) {
    float v = (threadIdx.x < 16) ? lpart[threadIdx.x] : 0.0f;
#pragma unroll
    for (int off = 8; off >= 1; off >>= 1) v += __shfl_down(v, off, 64);
    if (threadIdx.x == 0) out[0] = v * (1.0f / (2.0f * NPAIR));
}

extern "C" void kernel_launch(void* const* d_in, const int* in_sizes, int n_in,
                              void* d_out, int out_size, void* d_ws, size_t ws_size,
                              hipStream_t stream) {
    const float* X = (const float*)d_in[0];
    float* out = (float*)d_out;

    unsigned short* Pa = (unsigned short*)d_ws;                        // 2 MB
    unsigned short* Pb = Pa + (size_t)NROWS * DIM;                     // 2 MB
    float* partial = (float*)(Pb + (size_t)NROWS * DIM);               // 1 MB
    float* lpart = partial + (size_t)NROWS * CSPLIT;                   // 64 B

    k_pack<<<dim3((NROWS * DIM / 4) / 256), dim3(256), 0, stream>>>(X, Pa, Pb);
    k_rowsum<<<dim3(NROWS / ROWS_PER_BLOCK, CSPLIT), dim3(256), 0, stream>>>(Pa, Pb, partial);
    k_loss1<<<dim3(NPAIR / 256), dim3(256), 0, stream>>>(X, partial, lpart);
    k_final<<<dim3(1), dim3(64), 0, stream>>>(lpart, out);
}